// Round 4
// baseline (246.459 us; speedup 1.0000x reference)
//
#include <hip/hip_runtime.h>
#include <hip/hip_bf16.h>
#include <hip/hip_fp16.h>
#include <hip/hip_fp8.h>

#define N_NODES  50000
#define N_EDGES  800000
#define D        128
#define N_GRAPHS 64
#define CAP      64          // bucket capacity; in-deg ~ Poisson(16), P(>=64) ~ 1e-19
#define EW_SCALE 1048576.0f  // 2^20 fixed-point for packed weighted-degree
#define NB_GEMM1 391         // ceil(50000/128)
#define NB_FILL  3125        // 800000/256
#define PSTR     ((size_t)N_NODES * 64)   // plane stride bytes (3.2 MB < 4MiB XCD L2)

typedef _Float16 half8 __attribute__((ext_vector_type(8)));
typedef _Float16 half4 __attribute__((ext_vector_type(4)));
typedef float   float4v __attribute__((ext_vector_type(4)));
typedef float   f32x2   __attribute__((ext_vector_type(2)));

__device__ __forceinline__ float hu2f(unsigned short u) {
    __half_raw hr; hr.x = u;
    return __half2float(__half(hr));
}
__device__ __forceinline__ float fp8_f32(unsigned char u) {
    f32x2 v = __builtin_amdgcn_cvt_pk_f32_fp8((int)u, false);
    return v[0];
}
__device__ __forceinline__ unsigned char f32_fp8(float f) {
    __hip_fp8_e4m3 q(f);
    return (unsigned char)q.__x;
}
__device__ __forceinline__ void unpack_pd(unsigned long long p, int& n, float& dv) {
    int c = (int)(p >> 40);
    n = c < CAP ? c : CAP;
    dv = rsqrtf(1.0f + (float)(p & 0xFFFFFFFFFFULL) * (1.0f / EW_SCALE));
}

// ---------------------------------------------------------------------------
// FUSED: blocks [0,391) = gemm1 (x @ W1 -> FP8 e4m3 planes) on the MFMA pipe.
// blocks [391,3516) = fill (1 edge/thread, returning 64-bit atomic floor).
// Unchanged from round 3 (54.2 us, VALUBusy 4.6% -> at the atomic floor).
// ---------------------------------------------------------------------------
__global__ __launch_bounds__(256) void fused_gemm1_fill(const float* __restrict__ X,
                                                        const float* __restrict__ W,
                                                        unsigned char* __restrict__ Y8,
                                                        const int* __restrict__ ei,
                                                        const float* __restrict__ ew,
                                                        unsigned long long* __restrict__ packed,
                                                        unsigned int* __restrict__ bucket) {
    __shared__ _Float16 Xs[128][72];  // 18 KB, pitch 144 B
    __shared__ _Float16 Wt[128][72];  // 18 KB, transposed W1 (col-major)

    if (blockIdx.x >= NB_GEMM1) {
        int e = (blockIdx.x - NB_GEMM1) * 256 + threadIdx.x;
        if (e >= N_EDGES) return;
        int r = ei[e];
        int c = ei[N_EDGES + e];
        float w = ew[e];
        unsigned long long add = (1ULL << 40) | (unsigned long long)(unsigned)(w * EW_SCALE + 0.5f);
        unsigned long long old = atomicAdd(&packed[c], add);
        unsigned pos = (unsigned)(old >> 40);
        if (pos < CAP) {
            unsigned short wh = __half_as_ushort(__float2half_rn(w));
            bucket[(size_t)c * CAP + pos] = (unsigned)r | ((unsigned)wh << 16);
        }
        return;
    }

    const int tid  = threadIdx.x;
    const int row0 = blockIdx.x * 128;
    const int wv   = tid >> 6;        // 0..3 : col-tile pair
    const int lane = tid & 63;
    const int quad = lane >> 4;
    const int l16  = lane & 15;

    float4v acc[8][2] = {};

    for (int kt = 0; kt < 4; kt++) {
        const int kbase = kt * 32;
        {
            int r  = tid >> 1;
            int rr = row0 + r; if (rr >= N_NODES) rr = N_NODES - 1;
            int k0 = (tid & 1) * 16;
            const float4* src = (const float4*)(X + (size_t)rr * 128 + kbase + k0);
#pragma unroll
            for (int i = 0; i < 4; i++) {
                float4 v = src[i];
                half4 hv;
                hv[0] = (_Float16)v.x; hv[1] = (_Float16)v.y;
                hv[2] = (_Float16)v.z; hv[3] = (_Float16)v.w;
                *(half4*)(&Xs[r][k0 + i * 4]) = hv;
            }
        }
        {
            int k  = tid >> 3;               // 0..31
            int c0 = (tid & 7) * 16;
            const float4* src = (const float4*)(W + (size_t)(kbase + k) * 128 + c0);
#pragma unroll
            for (int i = 0; i < 4; i++) {
                float4 v = src[i];
                Wt[c0 + i * 4 + 0][k] = (_Float16)v.x;
                Wt[c0 + i * 4 + 1][k] = (_Float16)v.y;
                Wt[c0 + i * 4 + 2][k] = (_Float16)v.z;
                Wt[c0 + i * 4 + 3][k] = (_Float16)v.w;
            }
        }
        __syncthreads();

        half8 b0 = *(const half8*)(&Wt[wv * 32 + l16][quad * 8]);
        half8 b1f = *(const half8*)(&Wt[wv * 32 + 16 + l16][quad * 8]);
#pragma unroll
        for (int rt = 0; rt < 8; rt++) {
            half8 a = *(const half8*)(&Xs[rt * 16 + l16][quad * 8]);
            acc[rt][0] = __builtin_amdgcn_mfma_f32_16x16x32_f16(a, b0,  acc[rt][0], 0, 0, 0);
            acc[rt][1] = __builtin_amdgcn_mfma_f32_16x16x32_f16(a, b1f, acc[rt][1], 0, 0, 0);
        }
        __syncthreads();
    }
#pragma unroll
    for (int rt = 0; rt < 8; rt++)
#pragma unroll
        for (int ct = 0; ct < 2; ct++)
#pragma unroll
            for (int r = 0; r < 4; r++) {
                int row = row0 + rt * 16 + quad * 4 + r;
                int col = wv * 32 + ct * 16 + l16;
                if (row < N_NODES)
                    Y8[(size_t)(col >> 6) * PSTR + (size_t)row * 64 + (col & 63)] =
                        f32_fp8(acc[rt][ct][r]);
            }
}

// ---------------------------------------------------------------------------
// Layer-1 agg, ONE PLANE PER BLOCK with plane = blockIdx.x & 1.
// Blocks dispatch round-robin over the 8 XCDs, so even XCDs only ever gather
// plane 0 and odd XCDs plane 1 -> each XCD L2 holds one full 3.2-MB plane
// (fits 4 MiB) -> gathers become L2 hits (round-3 FETCH was 58.5 MB at 53%
// hit because both planes were live per XCD). ReLU is per-feature, so the
// halves decouple; h1 (fp16) goes to global via NT stores (no L2 pollution).
// 512 thr = 8 waves; 2 nodes/wave interleaved; 16 loads in flight per chunk.
// ---------------------------------------------------------------------------
__global__ __launch_bounds__(512) void agg1_plane_kernel(const unsigned char* __restrict__ x8in,
                                                         const unsigned long long* __restrict__ packed,
                                                         const unsigned int* __restrict__ bucket,
                                                         const float* __restrict__ b1,
                                                         _Float16* __restrict__ h1out) {
    const int p    = blockIdx.x & 1;
    const int grp  = blockIdx.x >> 1;
    const int wv   = threadIdx.x >> 6;     // 0..7
    const int lane = threadIdx.x & 63;
    const int node0 = grp * 16;

    const int nodeA = node0 + wv * 2;
    const int nodeB = nodeA + 1;
    int nA; float dvA; unpack_pd(packed[nodeA], nA, dvA);
    int nB; float dvB; unpack_pd(packed[nodeB], nB, dvB);

    unsigned pkA = 0u, pkB = 0u;
    if (lane < nA) {
        unsigned eh = __builtin_nontemporal_load(&bucket[(size_t)nodeA * CAP + lane]);
        int src = eh & 0xFFFFu;
        int sn; float sdv; unpack_pd(packed[src], sn, sdv);
        float v = hu2f((unsigned short)(eh >> 16)) * sdv;
        pkA = (unsigned)src | ((unsigned)__half_as_ushort(__float2half_rn(v)) << 16);
    }
    if (lane < nB) {
        unsigned eh = __builtin_nontemporal_load(&bucket[(size_t)nodeB * CAP + lane]);
        int src = eh & 0xFFFFu;
        int sn; float sdv; unpack_pd(packed[src], sn, sdv);
        float v = hu2f((unsigned short)(eh >> 16)) * sdv;
        pkB = (unsigned)src | ((unsigned)__half_as_ushort(__float2half_rn(v)) << 16);
    }
    int pkiA = (int)pkA, pkiB = (int)pkB;
    int nmax = nA > nB ? nA : nB;

    const unsigned char* pl = x8in + (size_t)p * PSTR;
    float aA = dvA * fp8_f32(pl[(size_t)nodeA * 64 + lane]);
    float aB = dvB * fp8_f32(pl[(size_t)nodeB * 64 + lane]);
    for (int i = 0; i < nmax; i += 8) {
        unsigned av[8], bv[8];
#pragma unroll
        for (int j = 0; j < 8; j++) {
            av[j] = (unsigned)__shfl(pkiA, i + j);
            bv[j] = (unsigned)__shfl(pkiB, i + j);
        }
        unsigned char mA[8], mB[8];
#pragma unroll
        for (int j = 0; j < 8; j++) mA[j] = pl[(size_t)(av[j] & 0xFFFFu) * 64 + lane];
#pragma unroll
        for (int j = 0; j < 8; j++) mB[j] = pl[(size_t)(bv[j] & 0xFFFFu) * 64 + lane];
#pragma unroll
        for (int j = 0; j < 8; j++)
            aA += hu2f((unsigned short)(av[j] >> 16)) * fp8_f32(mA[j]);
#pragma unroll
        for (int j = 0; j < 8; j++)
            aB += hu2f((unsigned short)(bv[j] >> 16)) * fp8_f32(mB[j]);
    }

    float bb = b1[p * 64 + lane];
    _Float16 hA = (_Float16)fmaxf(dvA * aA + bb, 0.0f);
    _Float16 hB = (_Float16)fmaxf(dvB * aB + bb, 0.0f);
    __builtin_nontemporal_store(hA, &h1out[(size_t)nodeA * 128 + p * 64 + lane]);
    __builtin_nontemporal_store(hB, &h1out[(size_t)nodeB * 128 + p * 64 + lane]);
}

// ---------------------------------------------------------------------------
// gemm2: x2 = (h1 @ W2) * dinv_row -> fp8 planes. h1 is already fp16; same
// MFMA tile structure as gemm1. 391 blocks x 256. ~6 us.
// ---------------------------------------------------------------------------
__global__ __launch_bounds__(256) void gemm2_kernel(const _Float16* __restrict__ H1,
                                                    const float* __restrict__ W,
                                                    const unsigned long long* __restrict__ packed,
                                                    unsigned char* __restrict__ Y8) {
    __shared__ _Float16 Xs[128][72];
    __shared__ _Float16 Wt[128][72];

    const int tid  = threadIdx.x;
    const int row0 = blockIdx.x * 128;
    const int wv   = tid >> 6;
    const int lane = tid & 63;
    const int quad = lane >> 4;
    const int l16  = lane & 15;

    float4v acc[8][2] = {};

    for (int kt = 0; kt < 4; kt++) {
        const int kbase = kt * 32;
        {
            int r  = tid >> 1;
            int rr = row0 + r; if (rr >= N_NODES) rr = N_NODES - 1;
            int k0 = (tid & 1) * 16;
            const half8* src = (const half8*)(H1 + (size_t)rr * 128 + kbase + k0);
            *(half8*)(&Xs[r][k0])     = src[0];
            *(half8*)(&Xs[r][k0 + 8]) = src[1];
        }
        {
            int k  = tid >> 3;               // 0..31
            int c0 = (tid & 7) * 16;
            const float4* src = (const float4*)(W + (size_t)(kbase + k) * 128 + c0);
#pragma unroll
            for (int i = 0; i < 4; i++) {
                float4 v = src[i];
                Wt[c0 + i * 4 + 0][k] = (_Float16)v.x;
                Wt[c0 + i * 4 + 1][k] = (_Float16)v.y;
                Wt[c0 + i * 4 + 2][k] = (_Float16)v.z;
                Wt[c0 + i * 4 + 3][k] = (_Float16)v.w;
            }
        }
        __syncthreads();

        half8 b0 = *(const half8*)(&Wt[wv * 32 + l16][quad * 8]);
        half8 b1f = *(const half8*)(&Wt[wv * 32 + 16 + l16][quad * 8]);
#pragma unroll
        for (int rt = 0; rt < 8; rt++) {
            half8 a = *(const half8*)(&Xs[rt * 16 + l16][quad * 8]);
            acc[rt][0] = __builtin_amdgcn_mfma_f32_16x16x32_f16(a, b0,  acc[rt][0], 0, 0, 0);
            acc[rt][1] = __builtin_amdgcn_mfma_f32_16x16x32_f16(a, b1f, acc[rt][1], 0, 0, 0);
        }
        __syncthreads();
    }
#pragma unroll
    for (int rt = 0; rt < 8; rt++)
#pragma unroll
        for (int ct = 0; ct < 2; ct++)
#pragma unroll
            for (int r = 0; r < 4; r++) {
                int row = row0 + rt * 16 + quad * 4 + r;
                int col = wv * 32 + ct * 16 + l16;
                if (row < N_NODES) {
                    int rn; float s;
                    unpack_pd(packed[row], rn, s);
                    Y8[(size_t)(col >> 6) * PSTR + (size_t)row * 64 + (col & 63)] =
                        f32_fp8(acc[rt][ct][r] * s);
                }
            }
}

// ---------------------------------------------------------------------------
// Layer-2 agg + partial head dot, one plane per block (blockIdx.x & 1).
// 256 thr = 4 waves, 2 nodes/wave -> 8 nodes/block; grid 2 x 6250.
// Per-plane partial dot (ReLU is per-feature); final2 sums both planes.
// ---------------------------------------------------------------------------
__global__ __launch_bounds__(256) void agg_head_plane(const unsigned char* __restrict__ x8,
                                                      const unsigned long long* __restrict__ packed,
                                                      const unsigned int* __restrict__ bucket,
                                                      const float* __restrict__ bias,
                                                      const float* __restrict__ Wh,
                                                      float* __restrict__ nodedot) {
    const int p    = blockIdx.x & 1;
    const int grp  = blockIdx.x >> 1;
    const int wv   = threadIdx.x >> 6;
    const int lane = threadIdx.x & 63;

    const int nodeA = grp * 8 + wv * 2;
    const int nodeB = nodeA + 1;
    int nA; float dvA; unpack_pd(packed[nodeA], nA, dvA);
    int nB; float dvB; unpack_pd(packed[nodeB], nB, dvB);

    unsigned ehA = (lane < nA) ? __builtin_nontemporal_load(&bucket[(size_t)nodeA * CAP + lane]) : 0u;
    unsigned ehB = (lane < nB) ? __builtin_nontemporal_load(&bucket[(size_t)nodeB * CAP + lane]) : 0u;
    int eiA = (int)ehA, eiB = (int)ehB;
    int nmax = nA > nB ? nA : nB;

    const unsigned char* pl = x8 + (size_t)p * PSTR;
    float aA = fp8_f32(pl[(size_t)nodeA * 64 + lane]);
    float aB = fp8_f32(pl[(size_t)nodeB * 64 + lane]);
    for (int i = 0; i < nmax; i += 8) {
        unsigned av[8], bv[8];
#pragma unroll
        for (int j = 0; j < 8; j++) {
            av[j] = (unsigned)__shfl(eiA, i + j);
            bv[j] = (unsigned)__shfl(eiB, i + j);
        }
        unsigned char mA[8], mB[8];
#pragma unroll
        for (int j = 0; j < 8; j++) mA[j] = pl[(size_t)(av[j] & 0xFFFFu) * 64 + lane];
#pragma unroll
        for (int j = 0; j < 8; j++) mB[j] = pl[(size_t)(bv[j] & 0xFFFFu) * 64 + lane];
#pragma unroll
        for (int j = 0; j < 8; j++)
            aA += hu2f((unsigned short)(av[j] >> 16)) * fp8_f32(mA[j]);
#pragma unroll
        for (int j = 0; j < 8; j++)
            aB += hu2f((unsigned short)(bv[j] >> 16)) * fp8_f32(mB[j]);
    }

    float bb = bias[p * 64 + lane];
    float ww = Wh[p * 64 + lane];
    float sA = fmaxf(dvA * aA + bb, 0.0f) * ww;
    float sB = fmaxf(dvB * aB + bb, 0.0f) * ww;
#pragma unroll
    for (int off = 32; off > 0; off >>= 1) {
        sA += __shfl_down(sA, off, 64);
        sB += __shfl_down(sB, off, 64);
    }
    if (lane == 0) {
        nodedot[(size_t)p * N_NODES + nodeA] = sA;
        nodedot[(size_t)p * N_NODES + nodeB] = sB;
    }
}

// ---------------------------------------------------------------------------
// out[g] = (sum of both plane partial dots over graph)/cnt + bh.
// ---------------------------------------------------------------------------
__global__ __launch_bounds__(256) void final2_kernel(const float* __restrict__ nodedot,
                                                     const int* __restrict__ batch,
                                                     const float* __restrict__ bh,
                                                     float* __restrict__ out) {
    __shared__ float red[256];
    int g = blockIdx.x;
    int lo = 0, hi = N_NODES;
    while (lo < hi) { int mid = (lo + hi) >> 1; if (batch[mid] < g) lo = mid + 1; else hi = mid; }
    int a = lo;
    hi = N_NODES;
    while (lo < hi) { int mid = (lo + hi) >> 1; if (batch[mid] < g + 1) lo = mid + 1; else hi = mid; }
    int b = lo;

    float s = 0.0f;
    for (int n = a + threadIdx.x; n < b; n += 256)
        s += nodedot[n] + nodedot[(size_t)N_NODES + n];
    red[threadIdx.x] = s;
    __syncthreads();
#pragma unroll
    for (int off = 128; off > 0; off >>= 1) {
        if (threadIdx.x < off) red[threadIdx.x] += red[threadIdx.x + off];
        __syncthreads();
    }
    if (threadIdx.x == 0)
        out[g] = red[0] / fmaxf((float)(b - a), 1.0f) + bh[0];
}

// ---------------------------------------------------------------------------
extern "C" void kernel_launch(void* const* d_in, const int* in_sizes, int n_in,
                              void* d_out, int out_size, void* d_ws, size_t ws_size,
                              hipStream_t stream) {
    const float* x   = (const float*)d_in[0];
    const float* ew  = (const float*)d_in[1];
    const float* W1  = (const float*)d_in[2];
    const float* b1  = (const float*)d_in[3];
    const float* W2  = (const float*)d_in[4];
    const float* b2  = (const float*)d_in[5];
    const float* Wh  = (const float*)d_in[6];
    const float* bh  = (const float*)d_in[7];
    const int*   ei  = (const int*)d_in[8];
    const int*   bat = (const int*)d_in[9];
    float* out = (float*)d_out;

    char* ws = (char*)d_ws;
    unsigned char* bufA8 = (unsigned char*)ws;            ws += (size_t)N_NODES * D;
    unsigned char* bufB8 = (unsigned char*)ws;            ws += (size_t)N_NODES * D;
    ws += 128 - ((size_t)ws & 127);                       // realign
    unsigned int* bucket = (unsigned int*)ws;             ws += (size_t)N_NODES * CAP * 4;
    unsigned long long* packed = (unsigned long long*)ws; ws += (size_t)N_NODES * 8;
    float*  nodedot = (float*)ws;                         ws += (size_t)N_NODES * 2 * 4;
    _Float16* h1buf = (_Float16*)ws;                      ws += (size_t)N_NODES * D * 2;

    hipMemsetAsync(packed, 0, (size_t)N_NODES * 8, stream);

    // gemm1 (x@W1 -> fp8 planes via MFMA fp16) overlapped with fill
    fused_gemm1_fill<<<NB_GEMM1 + NB_FILL, 256, 0, stream>>>(x, W1, bufA8, ei, ew, packed, bucket);

    // layer 1 agg: plane = blockIdx&1 -> XCD-resident 3.2MB working set
    agg1_plane_kernel<<<2 * 3125, 512, 0, stream>>>(bufA8, packed, bucket, b1, h1buf);

    // gemm2: h1 @ W2 (*dinv_row) -> x2 fp8 planes
    gemm2_kernel<<<NB_GEMM1, 256, 0, stream>>>(h1buf, W2, packed, bufB8);

    // layer 2 agg + partial head dot, plane = blockIdx&1
    agg_head_plane<<<2 * 6250, 256, 0, stream>>>(bufB8, packed, bucket, b2, Wh, nodedot);

    // segment-sum over both plane partials + head bias
    final2_kernel<<<N_GRAPHS, 256, 0, stream>>>(nodedot, bat, bh, out);
}

// Round 5
// 233.418 us; speedup vs baseline: 1.0559x; 1.0559x over previous
//
#include <hip/hip_runtime.h>
#include <hip/hip_bf16.h>
#include <hip/hip_fp16.h>
#include <hip/hip_fp8.h>

#define N_NODES  50000
#define N_EDGES  800000
#define D        128
#define N_GRAPHS 64
#define CAP      64          // bucket capacity; in-deg ~ Poisson(16), P(>=64) ~ 1e-19
#define EW_SCALE 1048576.0f  // 2^20 fixed-point for packed weighted-degree
#define NB_GEMM1 391         // ceil(50000/128)
#define NB_FILL  3125        // 800000/256
#define PSTR     ((size_t)N_NODES * 64)   // plane stride bytes (3.2 MB < 4MiB XCD L2)

typedef _Float16 half8 __attribute__((ext_vector_type(8)));
typedef _Float16 half4 __attribute__((ext_vector_type(4)));
typedef float   float4v __attribute__((ext_vector_type(4)));
typedef float   f32x2   __attribute__((ext_vector_type(2)));

__device__ __forceinline__ float hu2f(unsigned short u) {
    __half_raw hr; hr.x = u;
    return __half2float(__half(hr));
}
__device__ __forceinline__ float fp8_f32(unsigned char u) {
    f32x2 v = __builtin_amdgcn_cvt_pk_f32_fp8((int)u, false);
    return v[0];
}
__device__ __forceinline__ unsigned char f32_fp8(float f) {
    __hip_fp8_e4m3 q(f);
    return (unsigned char)q.__x;
}
__device__ __forceinline__ void unpack_pd(unsigned long long p, int& n, float& dv) {
    int c = (int)(p >> 40);
    n = c < CAP ? c : CAP;
    dv = rsqrtf(1.0f + (float)(p & 0xFFFFFFFFFFULL) * (1.0f / EW_SCALE));
}

// ---------------------------------------------------------------------------
// FUSED: blocks [0,391) = gemm1 (x @ W1 -> FP8 e4m3 planes) on the MFMA pipe.
// blocks [391,3516) = fill (1 edge/thread, returning 64-bit atomic floor).
// Unchanged (52 us, VALUBusy 4.6% -> at the returning-atomic floor).
// ---------------------------------------------------------------------------
__global__ __launch_bounds__(256) void fused_gemm1_fill(const float* __restrict__ X,
                                                        const float* __restrict__ W,
                                                        unsigned char* __restrict__ Y8,
                                                        const int* __restrict__ ei,
                                                        const float* __restrict__ ew,
                                                        unsigned long long* __restrict__ packed,
                                                        unsigned int* __restrict__ bucket) {
    __shared__ _Float16 Xs[128][72];  // 18 KB, pitch 144 B
    __shared__ _Float16 Wt[128][72];  // 18 KB, transposed W1 (col-major)

    if (blockIdx.x >= NB_GEMM1) {
        int e = (blockIdx.x - NB_GEMM1) * 256 + threadIdx.x;
        if (e >= N_EDGES) return;
        int r = ei[e];
        int c = ei[N_EDGES + e];
        float w = ew[e];
        unsigned long long add = (1ULL << 40) | (unsigned long long)(unsigned)(w * EW_SCALE + 0.5f);
        unsigned long long old = atomicAdd(&packed[c], add);
        unsigned pos = (unsigned)(old >> 40);
        if (pos < CAP) {
            unsigned short wh = __half_as_ushort(__float2half_rn(w));
            bucket[(size_t)c * CAP + pos] = (unsigned)r | ((unsigned)wh << 16);
        }
        return;
    }

    const int tid  = threadIdx.x;
    const int row0 = blockIdx.x * 128;
    const int wv   = tid >> 6;        // 0..3 : col-tile pair
    const int lane = tid & 63;
    const int quad = lane >> 4;
    const int l16  = lane & 15;

    float4v acc[8][2] = {};

    for (int kt = 0; kt < 4; kt++) {
        const int kbase = kt * 32;
        {
            int r  = tid >> 1;
            int rr = row0 + r; if (rr >= N_NODES) rr = N_NODES - 1;
            int k0 = (tid & 1) * 16;
            const float4* src = (const float4*)(X + (size_t)rr * 128 + kbase + k0);
#pragma unroll
            for (int i = 0; i < 4; i++) {
                float4 v = src[i];
                half4 hv;
                hv[0] = (_Float16)v.x; hv[1] = (_Float16)v.y;
                hv[2] = (_Float16)v.z; hv[3] = (_Float16)v.w;
                *(half4*)(&Xs[r][k0 + i * 4]) = hv;
            }
        }
        {
            int k  = tid >> 3;               // 0..31
            int c0 = (tid & 7) * 16;
            const float4* src = (const float4*)(W + (size_t)(kbase + k) * 128 + c0);
#pragma unroll
            for (int i = 0; i < 4; i++) {
                float4 v = src[i];
                Wt[c0 + i * 4 + 0][k] = (_Float16)v.x;
                Wt[c0 + i * 4 + 1][k] = (_Float16)v.y;
                Wt[c0 + i * 4 + 2][k] = (_Float16)v.z;
                Wt[c0 + i * 4 + 3][k] = (_Float16)v.w;
            }
        }
        __syncthreads();

        half8 b0 = *(const half8*)(&Wt[wv * 32 + l16][quad * 8]);
        half8 b1f = *(const half8*)(&Wt[wv * 32 + 16 + l16][quad * 8]);
#pragma unroll
        for (int rt = 0; rt < 8; rt++) {
            half8 a = *(const half8*)(&Xs[rt * 16 + l16][quad * 8]);
            acc[rt][0] = __builtin_amdgcn_mfma_f32_16x16x32_f16(a, b0,  acc[rt][0], 0, 0, 0);
            acc[rt][1] = __builtin_amdgcn_mfma_f32_16x16x32_f16(a, b1f, acc[rt][1], 0, 0, 0);
        }
        __syncthreads();
    }
#pragma unroll
    for (int rt = 0; rt < 8; rt++)
#pragma unroll
        for (int ct = 0; ct < 2; ct++)
#pragma unroll
            for (int r = 0; r < 4; r++) {
                int row = row0 + rt * 16 + quad * 4 + r;
                int col = wv * 32 + ct * 16 + l16;
                if (row < N_NODES)
                    Y8[(size_t)(col >> 6) * PSTR + (size_t)row * 64 + (col & 63)] =
                        f32_fp8(acc[rt][ct][r]);
            }
}

// ---------------------------------------------------------------------------
// Layer-1 agg, DWORD-GATHER: one wave-load covers 4 edges (lane group
// g=lane>>4 owns edge slot g; fl=lane&15 owns feature dword fl -> 4 fp8
// features via 2x cvt_pk_f32_fp8). 4x fewer load/shfl/addr instructions per
// edge than the byte-gather (round-4 was VALU-bound: VALUBusy 58%, FETCH
// already L2-resident at 20MB). Plane = blockIdx&1 keeps the XCD-affinity.
// Epilogue: shfl_xor(16,32) group-reduce, self-term added post-reduce.
// 512 thr = 8 waves; 2 nodes/wave interleaved; 4 gathers (16 lines) in
// flight per iter of 8 edges x 2 nodes.
// ---------------------------------------------------------------------------
__global__ __launch_bounds__(512) void agg1_plane_kernel(const unsigned char* __restrict__ x8in,
                                                         const unsigned long long* __restrict__ packed,
                                                         const unsigned int* __restrict__ bucket,
                                                         const float* __restrict__ b1,
                                                         _Float16* __restrict__ h1out) {
    const int p    = blockIdx.x & 1;
    const int grp  = blockIdx.x >> 1;
    const int wv   = threadIdx.x >> 6;     // 0..7
    const int lane = threadIdx.x & 63;
    const int g    = lane >> 4;            // edge sub-slot 0..3
    const int fl   = lane & 15;            // feature dword 0..15
    const int node0 = grp * 16;

    const int nodeA = node0 + wv * 2;
    const int nodeB = nodeA + 1;
    int nA; float dvA; unpack_pd(packed[nodeA], nA, dvA);
    int nB; float dvB; unpack_pd(packed[nodeB], nB, dvB);

    unsigned pkA = 0u, pkB = 0u;
    if (lane < nA) {
        unsigned eh = __builtin_nontemporal_load(&bucket[(size_t)nodeA * CAP + lane]);
        int src = eh & 0xFFFFu;
        int sn; float sdv; unpack_pd(packed[src], sn, sdv);
        float v = hu2f((unsigned short)(eh >> 16)) * sdv;
        pkA = (unsigned)src | ((unsigned)__half_as_ushort(__float2half_rn(v)) << 16);
    }
    if (lane < nB) {
        unsigned eh = __builtin_nontemporal_load(&bucket[(size_t)nodeB * CAP + lane]);
        int src = eh & 0xFFFFu;
        int sn; float sdv; unpack_pd(packed[src], sn, sdv);
        float v = hu2f((unsigned short)(eh >> 16)) * sdv;
        pkB = (unsigned)src | ((unsigned)__half_as_ushort(__float2half_rn(v)) << 16);
    }
    int pkiA = (int)pkA, pkiB = (int)pkB;
    int nmax = nA > nB ? nA : nB;

    const unsigned char* pl  = x8in + (size_t)p * PSTR;
    const unsigned char* plf = pl + fl * 4;

    float aA[4] = {}, aB[4] = {};
    for (int i = 0; i < nmax; i += 8) {
        unsigned hA0 = (unsigned)__shfl(pkiA, i + g);
        unsigned hA1 = (unsigned)__shfl(pkiA, i + 4 + g);
        unsigned hB0 = (unsigned)__shfl(pkiB, i + g);
        unsigned hB1 = (unsigned)__shfl(pkiB, i + 4 + g);
        unsigned dA0 = *(const unsigned*)(plf + (size_t)(hA0 & 0xFFFFu) * 64);
        unsigned dA1 = *(const unsigned*)(plf + (size_t)(hA1 & 0xFFFFu) * 64);
        unsigned dB0 = *(const unsigned*)(plf + (size_t)(hB0 & 0xFFFFu) * 64);
        unsigned dB1 = *(const unsigned*)(plf + (size_t)(hB1 & 0xFFFFu) * 64);
        float vA0 = hu2f((unsigned short)(hA0 >> 16));
        float vA1 = hu2f((unsigned short)(hA1 >> 16));
        float vB0 = hu2f((unsigned short)(hB0 >> 16));
        float vB1 = hu2f((unsigned short)(hB1 >> 16));
        f32x2 A0lo = __builtin_amdgcn_cvt_pk_f32_fp8((int)dA0, false);
        f32x2 A0hi = __builtin_amdgcn_cvt_pk_f32_fp8((int)dA0, true);
        f32x2 A1lo = __builtin_amdgcn_cvt_pk_f32_fp8((int)dA1, false);
        f32x2 A1hi = __builtin_amdgcn_cvt_pk_f32_fp8((int)dA1, true);
        f32x2 B0lo = __builtin_amdgcn_cvt_pk_f32_fp8((int)dB0, false);
        f32x2 B0hi = __builtin_amdgcn_cvt_pk_f32_fp8((int)dB0, true);
        f32x2 B1lo = __builtin_amdgcn_cvt_pk_f32_fp8((int)dB1, false);
        f32x2 B1hi = __builtin_amdgcn_cvt_pk_f32_fp8((int)dB1, true);
        aA[0] += vA0 * A0lo[0] + vA1 * A1lo[0];
        aA[1] += vA0 * A0lo[1] + vA1 * A1lo[1];
        aA[2] += vA0 * A0hi[0] + vA1 * A1hi[0];
        aA[3] += vA0 * A0hi[1] + vA1 * A1hi[1];
        aB[0] += vB0 * B0lo[0] + vB1 * B1lo[0];
        aB[1] += vB0 * B0lo[1] + vB1 * B1lo[1];
        aB[2] += vB0 * B0hi[0] + vB1 * B1hi[0];
        aB[3] += vB0 * B0hi[1] + vB1 * B1hi[1];
    }

    // reduce over the 4 edge-slot groups (lanes xor 16, 32)
#pragma unroll
    for (int k = 0; k < 4; k++) {
        aA[k] += __shfl_xor(aA[k], 16, 64);
        aA[k] += __shfl_xor(aA[k], 32, 64);
        aB[k] += __shfl_xor(aB[k], 16, 64);
        aB[k] += __shfl_xor(aB[k], 32, 64);
    }

    // self-loop term (post-reduction: added exactly once, consistent per lane)
    unsigned dsA = *(const unsigned*)(plf + (size_t)nodeA * 64);
    unsigned dsB = *(const unsigned*)(plf + (size_t)nodeB * 64);
    f32x2 sAlo = __builtin_amdgcn_cvt_pk_f32_fp8((int)dsA, false);
    f32x2 sAhi = __builtin_amdgcn_cvt_pk_f32_fp8((int)dsA, true);
    f32x2 sBlo = __builtin_amdgcn_cvt_pk_f32_fp8((int)dsB, false);
    f32x2 sBhi = __builtin_amdgcn_cvt_pk_f32_fp8((int)dsB, true);
    aA[0] += dvA * sAlo[0]; aA[1] += dvA * sAlo[1];
    aA[2] += dvA * sAhi[0]; aA[3] += dvA * sAhi[1];
    aB[0] += dvB * sBlo[0]; aB[1] += dvB * sBlo[1];
    aB[2] += dvB * sBhi[0]; aB[3] += dvB * sBhi[1];

    if (g == 0) {
        half4 hvA, hvB;
#pragma unroll
        for (int k = 0; k < 4; k++) {
            float bb = b1[p * 64 + fl * 4 + k];
            hvA[k] = (_Float16)fmaxf(dvA * aA[k] + bb, 0.0f);
            hvB[k] = (_Float16)fmaxf(dvB * aB[k] + bb, 0.0f);
        }
        __builtin_nontemporal_store(hvA, (half4*)&h1out[(size_t)nodeA * 128 + p * 64 + fl * 4]);
        __builtin_nontemporal_store(hvB, (half4*)&h1out[(size_t)nodeB * 128 + p * 64 + fl * 4]);
    }
}

// ---------------------------------------------------------------------------
// gemm2: x2 = (h1 @ W2) * dinv_row -> fp8 planes. h1 fp16; same MFMA tile
// structure as gemm1. 391 blocks x 256. ~6-10 us.
// ---------------------------------------------------------------------------
__global__ __launch_bounds__(256) void gemm2_kernel(const _Float16* __restrict__ H1,
                                                    const float* __restrict__ W,
                                                    const unsigned long long* __restrict__ packed,
                                                    unsigned char* __restrict__ Y8) {
    __shared__ _Float16 Xs[128][72];
    __shared__ _Float16 Wt[128][72];

    const int tid  = threadIdx.x;
    const int row0 = blockIdx.x * 128;
    const int wv   = tid >> 6;
    const int lane = tid & 63;
    const int quad = lane >> 4;
    const int l16  = lane & 15;

    float4v acc[8][2] = {};

    for (int kt = 0; kt < 4; kt++) {
        const int kbase = kt * 32;
        {
            int r  = tid >> 1;
            int rr = row0 + r; if (rr >= N_NODES) rr = N_NODES - 1;
            int k0 = (tid & 1) * 16;
            const half8* src = (const half8*)(H1 + (size_t)rr * 128 + kbase + k0);
            *(half8*)(&Xs[r][k0])     = src[0];
            *(half8*)(&Xs[r][k0 + 8]) = src[1];
        }
        {
            int k  = tid >> 3;               // 0..31
            int c0 = (tid & 7) * 16;
            const float4* src = (const float4*)(W + (size_t)(kbase + k) * 128 + c0);
#pragma unroll
            for (int i = 0; i < 4; i++) {
                float4 v = src[i];
                Wt[c0 + i * 4 + 0][k] = (_Float16)v.x;
                Wt[c0 + i * 4 + 1][k] = (_Float16)v.y;
                Wt[c0 + i * 4 + 2][k] = (_Float16)v.z;
                Wt[c0 + i * 4 + 3][k] = (_Float16)v.w;
            }
        }
        __syncthreads();

        half8 b0 = *(const half8*)(&Wt[wv * 32 + l16][quad * 8]);
        half8 b1f = *(const half8*)(&Wt[wv * 32 + 16 + l16][quad * 8]);
#pragma unroll
        for (int rt = 0; rt < 8; rt++) {
            half8 a = *(const half8*)(&Xs[rt * 16 + l16][quad * 8]);
            acc[rt][0] = __builtin_amdgcn_mfma_f32_16x16x32_f16(a, b0,  acc[rt][0], 0, 0, 0);
            acc[rt][1] = __builtin_amdgcn_mfma_f32_16x16x32_f16(a, b1f, acc[rt][1], 0, 0, 0);
        }
        __syncthreads();
    }
#pragma unroll
    for (int rt = 0; rt < 8; rt++)
#pragma unroll
        for (int ct = 0; ct < 2; ct++)
#pragma unroll
            for (int r = 0; r < 4; r++) {
                int row = row0 + rt * 16 + quad * 4 + r;
                int col = wv * 32 + ct * 16 + l16;
                if (row < N_NODES) {
                    int rn; float s;
                    unpack_pd(packed[row], rn, s);
                    Y8[(size_t)(col >> 6) * PSTR + (size_t)row * 64 + (col & 63)] =
                        f32_fp8(acc[rt][ct][r] * s);
                }
            }
}

// ---------------------------------------------------------------------------
// Layer-2 agg + partial head dot, dword-gather version. Plane = blockIdx&1.
// 256 thr = 4 waves, 2 nodes/wave -> 8 nodes/block; grid 2 x 6250.
// ---------------------------------------------------------------------------
__global__ __launch_bounds__(256) void agg_head_plane(const unsigned char* __restrict__ x8,
                                                      const unsigned long long* __restrict__ packed,
                                                      const unsigned int* __restrict__ bucket,
                                                      const float* __restrict__ bias,
                                                      const float* __restrict__ Wh,
                                                      float* __restrict__ nodedot) {
    const int p    = blockIdx.x & 1;
    const int grp  = blockIdx.x >> 1;
    const int wv   = threadIdx.x >> 6;
    const int lane = threadIdx.x & 63;
    const int g    = lane >> 4;
    const int fl   = lane & 15;

    const int nodeA = grp * 8 + wv * 2;
    const int nodeB = nodeA + 1;
    int nA; float dvA; unpack_pd(packed[nodeA], nA, dvA);
    int nB; float dvB; unpack_pd(packed[nodeB], nB, dvB);

    unsigned ehA = (lane < nA) ? __builtin_nontemporal_load(&bucket[(size_t)nodeA * CAP + lane]) : 0u;
    unsigned ehB = (lane < nB) ? __builtin_nontemporal_load(&bucket[(size_t)nodeB * CAP + lane]) : 0u;
    int eiA = (int)ehA, eiB = (int)ehB;
    int nmax = nA > nB ? nA : nB;

    const unsigned char* pl  = x8 + (size_t)p * PSTR;
    const unsigned char* plf = pl + fl * 4;

    float aA[4] = {}, aB[4] = {};
    for (int i = 0; i < nmax; i += 8) {
        unsigned hA0 = (unsigned)__shfl(eiA, i + g);
        unsigned hA1 = (unsigned)__shfl(eiA, i + 4 + g);
        unsigned hB0 = (unsigned)__shfl(eiB, i + g);
        unsigned hB1 = (unsigned)__shfl(eiB, i + 4 + g);
        unsigned dA0 = *(const unsigned*)(plf + (size_t)(hA0 & 0xFFFFu) * 64);
        unsigned dA1 = *(const unsigned*)(plf + (size_t)(hA1 & 0xFFFFu) * 64);
        unsigned dB0 = *(const unsigned*)(plf + (size_t)(hB0 & 0xFFFFu) * 64);
        unsigned dB1 = *(const unsigned*)(plf + (size_t)(hB1 & 0xFFFFu) * 64);
        float vA0 = hu2f((unsigned short)(hA0 >> 16));
        float vA1 = hu2f((unsigned short)(hA1 >> 16));
        float vB0 = hu2f((unsigned short)(hB0 >> 16));
        float vB1 = hu2f((unsigned short)(hB1 >> 16));
        f32x2 A0lo = __builtin_amdgcn_cvt_pk_f32_fp8((int)dA0, false);
        f32x2 A0hi = __builtin_amdgcn_cvt_pk_f32_fp8((int)dA0, true);
        f32x2 A1lo = __builtin_amdgcn_cvt_pk_f32_fp8((int)dA1, false);
        f32x2 A1hi = __builtin_amdgcn_cvt_pk_f32_fp8((int)dA1, true);
        f32x2 B0lo = __builtin_amdgcn_cvt_pk_f32_fp8((int)dB0, false);
        f32x2 B0hi = __builtin_amdgcn_cvt_pk_f32_fp8((int)dB0, true);
        f32x2 B1lo = __builtin_amdgcn_cvt_pk_f32_fp8((int)dB1, false);
        f32x2 B1hi = __builtin_amdgcn_cvt_pk_f32_fp8((int)dB1, true);
        aA[0] += vA0 * A0lo[0] + vA1 * A1lo[0];
        aA[1] += vA0 * A0lo[1] + vA1 * A1lo[1];
        aA[2] += vA0 * A0hi[0] + vA1 * A1hi[0];
        aA[3] += vA0 * A0hi[1] + vA1 * A1hi[1];
        aB[0] += vB0 * B0lo[0] + vB1 * B1lo[0];
        aB[1] += vB0 * B0lo[1] + vB1 * B1lo[1];
        aB[2] += vB0 * B0hi[0] + vB1 * B1hi[0];
        aB[3] += vB0 * B0hi[1] + vB1 * B1hi[1];
    }

#pragma unroll
    for (int k = 0; k < 4; k++) {
        aA[k] += __shfl_xor(aA[k], 16, 64);
        aA[k] += __shfl_xor(aA[k], 32, 64);
        aB[k] += __shfl_xor(aB[k], 16, 64);
        aB[k] += __shfl_xor(aB[k], 32, 64);
    }

    unsigned dsA = *(const unsigned*)(plf + (size_t)nodeA * 64);
    unsigned dsB = *(const unsigned*)(plf + (size_t)nodeB * 64);
    f32x2 sAlo = __builtin_amdgcn_cvt_pk_f32_fp8((int)dsA, false);
    f32x2 sAhi = __builtin_amdgcn_cvt_pk_f32_fp8((int)dsA, true);
    f32x2 sBlo = __builtin_amdgcn_cvt_pk_f32_fp8((int)dsB, false);
    f32x2 sBhi = __builtin_amdgcn_cvt_pk_f32_fp8((int)dsB, true);
    aA[0] += sAlo[0]; aA[1] += sAlo[1]; aA[2] += sAhi[0]; aA[3] += sAhi[1];
    aB[0] += sBlo[0]; aB[1] += sBlo[1]; aB[2] += sBhi[0]; aB[3] += sBhi[1];

    float sA = 0.0f, sB = 0.0f;
#pragma unroll
    for (int k = 0; k < 4; k++) {
        int f = p * 64 + fl * 4 + k;
        float bb = bias[f];
        float ww = Wh[f];
        sA += fmaxf(dvA * aA[k] + bb, 0.0f) * ww;
        sB += fmaxf(dvB * aB[k] + bb, 0.0f) * ww;
    }
    // reduce over fl (16 lanes per group; groups already hold identical sums)
#pragma unroll
    for (int off = 8; off > 0; off >>= 1) {
        sA += __shfl_xor(sA, off, 64);
        sB += __shfl_xor(sB, off, 64);
    }
    if (lane == 0) {
        nodedot[(size_t)p * N_NODES + nodeA] = sA;
        nodedot[(size_t)p * N_NODES + nodeB] = sB;
    }
}

// ---------------------------------------------------------------------------
// out[g] = (sum of both plane partial dots over graph)/cnt + bh.
// ---------------------------------------------------------------------------
__global__ __launch_bounds__(256) void final2_kernel(const float* __restrict__ nodedot,
                                                     const int* __restrict__ batch,
                                                     const float* __restrict__ bh,
                                                     float* __restrict__ out) {
    __shared__ float red[256];
    int g = blockIdx.x;
    int lo = 0, hi = N_NODES;
    while (lo < hi) { int mid = (lo + hi) >> 1; if (batch[mid] < g) lo = mid + 1; else hi = mid; }
    int a = lo;
    hi = N_NODES;
    while (lo < hi) { int mid = (lo + hi) >> 1; if (batch[mid] < g + 1) lo = mid + 1; else hi = mid; }
    int b = lo;

    float s = 0.0f;
    for (int n = a + threadIdx.x; n < b; n += 256)
        s += nodedot[n] + nodedot[(size_t)N_NODES + n];
    red[threadIdx.x] = s;
    __syncthreads();
#pragma unroll
    for (int off = 128; off > 0; off >>= 1) {
        if (threadIdx.x < off) red[threadIdx.x] += red[threadIdx.x + off];
        __syncthreads();
    }
    if (threadIdx.x == 0)
        out[g] = red[0] / fmaxf((float)(b - a), 1.0f) + bh[0];
}

// ---------------------------------------------------------------------------
extern "C" void kernel_launch(void* const* d_in, const int* in_sizes, int n_in,
                              void* d_out, int out_size, void* d_ws, size_t ws_size,
                              hipStream_t stream) {
    const float* x   = (const float*)d_in[0];
    const float* ew  = (const float*)d_in[1];
    const float* W1  = (const float*)d_in[2];
    const float* b1  = (const float*)d_in[3];
    const float* W2  = (const float*)d_in[4];
    const float* b2  = (const float*)d_in[5];
    const float* Wh  = (const float*)d_in[6];
    const float* bh  = (const float*)d_in[7];
    const int*   ei  = (const int*)d_in[8];
    const int*   bat = (const int*)d_in[9];
    float* out = (float*)d_out;

    char* ws = (char*)d_ws;
    unsigned char* bufA8 = (unsigned char*)ws;            ws += (size_t)N_NODES * D;
    unsigned char* bufB8 = (unsigned char*)ws;            ws += (size_t)N_NODES * D;
    ws += 128 - ((size_t)ws & 127);                       // realign
    unsigned int* bucket = (unsigned int*)ws;             ws += (size_t)N_NODES * CAP * 4;
    unsigned long long* packed = (unsigned long long*)ws; ws += (size_t)N_NODES * 8;
    float*  nodedot = (float*)ws;                         ws += (size_t)N_NODES * 2 * 4;
    _Float16* h1buf = (_Float16*)ws;                      ws += (size_t)N_NODES * D * 2;

    hipMemsetAsync(packed, 0, (size_t)N_NODES * 8, stream);

    // gemm1 (x@W1 -> fp8 planes via MFMA fp16) overlapped with fill
    fused_gemm1_fill<<<NB_GEMM1 + NB_FILL, 256, 0, stream>>>(x, W1, bufA8, ei, ew, packed, bucket);

    // layer 1 agg: dword-gather, plane = blockIdx&1 (XCD-resident 3.2MB)
    agg1_plane_kernel<<<2 * 3125, 512, 0, stream>>>(bufA8, packed, bucket, b1, h1buf);

    // gemm2: h1 @ W2 (*dinv_row) -> x2 fp8 planes
    gemm2_kernel<<<NB_GEMM1, 256, 0, stream>>>(h1buf, W2, packed, bufB8);

    // layer 2 agg + partial head dot, dword-gather, plane = blockIdx&1
    agg_head_plane<<<2 * 6250, 256, 0, stream>>>(bufB8, packed, bucket, b2, Wh, nodedot);

    // segment-sum over both plane partials + head bias
    final2_kernel<<<N_GRAPHS, 256, 0, stream>>>(nodedot, bat, bh, out);
}

// Round 6
// 209.380 us; speedup vs baseline: 1.1771x; 1.1148x over previous
//
#include <hip/hip_runtime.h>
#include <hip/hip_bf16.h>
#include <hip/hip_fp16.h>
#include <hip/hip_fp8.h>

#define N_NODES  50000
#define N_EDGES  800000
#define D        128
#define N_GRAPHS 64
#define CAP      64          // bucket capacity; in-deg ~ Poisson(16), P(>=64) ~ 1e-19
#define EW_SCALE 1048576.0f  // 2^20 fixed-point for packed weighted-degree
#define NB_GEMM1 391         // ceil(50000/128)
#define NB_FILL  3125        // 800000/256
#define NB_AGG16 3125        // N_NODES/16

typedef _Float16 half8 __attribute__((ext_vector_type(8)));
typedef _Float16 half4 __attribute__((ext_vector_type(4)));
typedef float   float4v __attribute__((ext_vector_type(4)));
typedef float   f32x2   __attribute__((ext_vector_type(2)));

__device__ __forceinline__ float hu2f(unsigned short u) {
    __half_raw hr; hr.x = u;
    return __half2float(__half(hr));
}
__device__ __forceinline__ unsigned char f32_fp8(float f) {
    __hip_fp8_e4m3 q(f);
    return (unsigned char)q.__x;
}
__device__ __forceinline__ void unpack_pd(unsigned long long p, int& n, float& dv) {
    int c = (int)(p >> 40);
    n = c < CAP ? c : CAP;
    dv = rsqrtf(1.0f + (float)(p & 0xFFFFFFFFFFULL) * (1.0f / EW_SCALE));
}

// ---------------------------------------------------------------------------
// FUSED: blocks [0,391) = gemm1 (x @ W1 -> FP8 e4m3 rows) on the MFMA pipe.
// blocks [391,3516) = fill (1 edge/thread, returning 64-bit atomic floor
// ~50 us). Y8 is a plain row-major [N][128] fp8 array (planes abandoned:
// XCD-residency worked — FETCH 58->20MB — but its structural tax, duplicated
// headers + extra dispatch + h1 round-trip, exceeded the win).
// ---------------------------------------------------------------------------
__global__ __launch_bounds__(256) void fused_gemm1_fill(const float* __restrict__ X,
                                                        const float* __restrict__ W,
                                                        unsigned char* __restrict__ Y8,
                                                        const int* __restrict__ ei,
                                                        const float* __restrict__ ew,
                                                        unsigned long long* __restrict__ packed,
                                                        unsigned int* __restrict__ bucket) {
    __shared__ _Float16 Xs[128][72];  // 18 KB, pitch 144 B
    __shared__ _Float16 Wt[128][72];  // 18 KB, transposed W1 (col-major)

    if (blockIdx.x >= NB_GEMM1) {
        int e = (blockIdx.x - NB_GEMM1) * 256 + threadIdx.x;
        if (e >= N_EDGES) return;
        int r = ei[e];
        int c = ei[N_EDGES + e];
        float w = ew[e];
        unsigned long long add = (1ULL << 40) | (unsigned long long)(unsigned)(w * EW_SCALE + 0.5f);
        unsigned long long old = atomicAdd(&packed[c], add);
        unsigned pos = (unsigned)(old >> 40);
        if (pos < CAP) {
            unsigned short wh = __half_as_ushort(__float2half_rn(w));
            bucket[(size_t)c * CAP + pos] = (unsigned)r | ((unsigned)wh << 16);
        }
        return;
    }

    const int tid  = threadIdx.x;
    const int row0 = blockIdx.x * 128;
    const int wv   = tid >> 6;        // 0..3 : col-tile pair
    const int lane = tid & 63;
    const int quad = lane >> 4;
    const int l16  = lane & 15;

    float4v acc[8][2] = {};

    for (int kt = 0; kt < 4; kt++) {
        const int kbase = kt * 32;
        {
            int r  = tid >> 1;
            int rr = row0 + r; if (rr >= N_NODES) rr = N_NODES - 1;
            int k0 = (tid & 1) * 16;
            const float4* src = (const float4*)(X + (size_t)rr * 128 + kbase + k0);
#pragma unroll
            for (int i = 0; i < 4; i++) {
                float4 v = src[i];
                half4 hv;
                hv[0] = (_Float16)v.x; hv[1] = (_Float16)v.y;
                hv[2] = (_Float16)v.z; hv[3] = (_Float16)v.w;
                *(half4*)(&Xs[r][k0 + i * 4]) = hv;
            }
        }
        {
            int k  = tid >> 3;               // 0..31
            int c0 = (tid & 7) * 16;
            const float4* src = (const float4*)(W + (size_t)(kbase + k) * 128 + c0);
#pragma unroll
            for (int i = 0; i < 4; i++) {
                float4 v = src[i];
                Wt[c0 + i * 4 + 0][k] = (_Float16)v.x;
                Wt[c0 + i * 4 + 1][k] = (_Float16)v.y;
                Wt[c0 + i * 4 + 2][k] = (_Float16)v.z;
                Wt[c0 + i * 4 + 3][k] = (_Float16)v.w;
            }
        }
        __syncthreads();

        half8 b0 = *(const half8*)(&Wt[wv * 32 + l16][quad * 8]);
        half8 b1f = *(const half8*)(&Wt[wv * 32 + 16 + l16][quad * 8]);
#pragma unroll
        for (int rt = 0; rt < 8; rt++) {
            half8 a = *(const half8*)(&Xs[rt * 16 + l16][quad * 8]);
            acc[rt][0] = __builtin_amdgcn_mfma_f32_16x16x32_f16(a, b0,  acc[rt][0], 0, 0, 0);
            acc[rt][1] = __builtin_amdgcn_mfma_f32_16x16x32_f16(a, b1f, acc[rt][1], 0, 0, 0);
        }
        __syncthreads();
    }
#pragma unroll
    for (int rt = 0; rt < 8; rt++)
#pragma unroll
        for (int ct = 0; ct < 2; ct++)
#pragma unroll
            for (int r = 0; r < 4; r++) {
                int row = row0 + rt * 16 + quad * 4 + r;
                int col = wv * 32 + ct * 16 + l16;
                if (row < N_NODES)
                    Y8[(size_t)row * 128 + col] = f32_fp8(acc[rt][ct][r]);
            }
}

// ---------------------------------------------------------------------------
// Layer-1 agg + gemm2 RE-FUSED, FULL-ROW uint2 dword-gather:
// lane group g=lane>>4 owns edge slot g; fl=lane&15 loads uint2 = 8 fp8
// features -> one wave-load covers 4 edges x full 128-feature row
// (~3.75 VALU-instr/edge-row vs 17 byte-gather). Header runs ONCE per node.
// Group-reduce via shfl_xor(16,32); self-term post-reduce; h1 -> LDS fp16;
// round-1-verified MFMA gemm2 epilogue writes x2 fp8 rows.
// 512 thr = 8 waves; 16 nodes/block; 3125 blocks.
// ---------------------------------------------------------------------------
__global__ __launch_bounds__(512) void agg1_gemm2_kernel(const unsigned char* __restrict__ x8in,
                                                         const unsigned long long* __restrict__ packed,
                                                         const unsigned int* __restrict__ bucket,
                                                         const float* __restrict__ b1,
                                                         const float* __restrict__ W2,
                                                         unsigned char* __restrict__ x2) {
    __shared__ _Float16 sh1[16][136];
    const int wv   = threadIdx.x >> 6;     // 0..7
    const int lane = threadIdx.x & 63;
    const int g    = lane >> 4;            // edge sub-slot 0..3
    const int fl   = lane & 15;            // feature octet 0..15
    const int node0 = blockIdx.x * 16;

    const int nodeA = node0 + wv * 2;
    const int nodeB = nodeA + 1;
    int nA; float dvA; unpack_pd(packed[nodeA], nA, dvA);
    int nB; float dvB; unpack_pd(packed[nodeB], nB, dvB);

    unsigned pkA = 0u, pkB = 0u;
    if (lane < nA) {
        unsigned eh = __builtin_nontemporal_load(&bucket[(size_t)nodeA * CAP + lane]);
        int src = eh & 0xFFFFu;
        int sn; float sdv; unpack_pd(packed[src], sn, sdv);
        float v = hu2f((unsigned short)(eh >> 16)) * sdv;
        pkA = (unsigned)src | ((unsigned)__half_as_ushort(__float2half_rn(v)) << 16);
    }
    if (lane < nB) {
        unsigned eh = __builtin_nontemporal_load(&bucket[(size_t)nodeB * CAP + lane]);
        int src = eh & 0xFFFFu;
        int sn; float sdv; unpack_pd(packed[src], sn, sdv);
        float v = hu2f((unsigned short)(eh >> 16)) * sdv;
        pkB = (unsigned)src | ((unsigned)__half_as_ushort(__float2half_rn(v)) << 16);
    }
    int pkiA = (int)pkA, pkiB = (int)pkB;
    int nmax = nA > nB ? nA : nB;

    const unsigned char* base = x8in + fl * 8;   // lane's byte offset in row

    float aA[8] = {}, aB[8] = {};
    for (int i = 0; i < nmax; i += 8) {
        unsigned hA0 = (unsigned)__shfl(pkiA, i + g);
        unsigned hA1 = (unsigned)__shfl(pkiA, i + 4 + g);
        unsigned hB0 = (unsigned)__shfl(pkiB, i + g);
        unsigned hB1 = (unsigned)__shfl(pkiB, i + 4 + g);
        uint2 dA0 = *(const uint2*)(base + (size_t)(hA0 & 0xFFFFu) * 128);
        uint2 dA1 = *(const uint2*)(base + (size_t)(hA1 & 0xFFFFu) * 128);
        uint2 dB0 = *(const uint2*)(base + (size_t)(hB0 & 0xFFFFu) * 128);
        uint2 dB1 = *(const uint2*)(base + (size_t)(hB1 & 0xFFFFu) * 128);
        float vA0 = hu2f((unsigned short)(hA0 >> 16));
        float vA1 = hu2f((unsigned short)(hA1 >> 16));
        float vB0 = hu2f((unsigned short)(hB0 >> 16));
        float vB1 = hu2f((unsigned short)(hB1 >> 16));
#pragma unroll
        for (int d = 0; d < 2; d++) {
            unsigned wA0 = d ? dA0.y : dA0.x;
            unsigned wA1 = d ? dA1.y : dA1.x;
            unsigned wB0 = d ? dB0.y : dB0.x;
            unsigned wB1 = d ? dB1.y : dB1.x;
            f32x2 A0lo = __builtin_amdgcn_cvt_pk_f32_fp8((int)wA0, false);
            f32x2 A0hi = __builtin_amdgcn_cvt_pk_f32_fp8((int)wA0, true);
            f32x2 A1lo = __builtin_amdgcn_cvt_pk_f32_fp8((int)wA1, false);
            f32x2 A1hi = __builtin_amdgcn_cvt_pk_f32_fp8((int)wA1, true);
            f32x2 B0lo = __builtin_amdgcn_cvt_pk_f32_fp8((int)wB0, false);
            f32x2 B0hi = __builtin_amdgcn_cvt_pk_f32_fp8((int)wB0, true);
            f32x2 B1lo = __builtin_amdgcn_cvt_pk_f32_fp8((int)wB1, false);
            f32x2 B1hi = __builtin_amdgcn_cvt_pk_f32_fp8((int)wB1, true);
            aA[d*4+0] += vA0 * A0lo[0] + vA1 * A1lo[0];
            aA[d*4+1] += vA0 * A0lo[1] + vA1 * A1lo[1];
            aA[d*4+2] += vA0 * A0hi[0] + vA1 * A1hi[0];
            aA[d*4+3] += vA0 * A0hi[1] + vA1 * A1hi[1];
            aB[d*4+0] += vB0 * B0lo[0] + vB1 * B1lo[0];
            aB[d*4+1] += vB0 * B0lo[1] + vB1 * B1lo[1];
            aB[d*4+2] += vB0 * B0hi[0] + vB1 * B1hi[0];
            aB[d*4+3] += vB0 * B0hi[1] + vB1 * B1hi[1];
        }
    }

    // reduce over the 4 edge-slot groups (lanes xor 16, 32)
#pragma unroll
    for (int k = 0; k < 8; k++) {
        aA[k] += __shfl_xor(aA[k], 16, 64);
        aA[k] += __shfl_xor(aA[k], 32, 64);
        aB[k] += __shfl_xor(aB[k], 16, 64);
        aB[k] += __shfl_xor(aB[k], 32, 64);
    }

    // self-loop term (post-reduction: added exactly once)
    {
        uint2 dsA = *(const uint2*)(base + (size_t)nodeA * 128);
        uint2 dsB = *(const uint2*)(base + (size_t)nodeB * 128);
#pragma unroll
        for (int d = 0; d < 2; d++) {
            unsigned wA = d ? dsA.y : dsA.x;
            unsigned wB = d ? dsB.y : dsB.x;
            f32x2 Alo = __builtin_amdgcn_cvt_pk_f32_fp8((int)wA, false);
            f32x2 Ahi = __builtin_amdgcn_cvt_pk_f32_fp8((int)wA, true);
            f32x2 Blo = __builtin_amdgcn_cvt_pk_f32_fp8((int)wB, false);
            f32x2 Bhi = __builtin_amdgcn_cvt_pk_f32_fp8((int)wB, true);
            aA[d*4+0] += dvA * Alo[0]; aA[d*4+1] += dvA * Alo[1];
            aA[d*4+2] += dvA * Ahi[0]; aA[d*4+3] += dvA * Ahi[1];
            aB[d*4+0] += dvB * Blo[0]; aB[d*4+1] += dvB * Blo[1];
            aB[d*4+2] += dvB * Bhi[0]; aB[d*4+3] += dvB * Bhi[1];
        }
    }

    if (g == 0) {
        float4 bb0 = ((const float4*)b1)[fl * 2];
        float4 bb1 = ((const float4*)b1)[fl * 2 + 1];
        float bb[8] = {bb0.x, bb0.y, bb0.z, bb0.w, bb1.x, bb1.y, bb1.z, bb1.w};
        half8 hvA, hvB;
#pragma unroll
        for (int k = 0; k < 8; k++) {
            hvA[k] = (_Float16)fmaxf(dvA * aA[k] + bb[k], 0.0f);
            hvB[k] = (_Float16)fmaxf(dvB * aB[k] + bb[k], 0.0f);
        }
        *(half8*)(&sh1[wv * 2][fl * 8])     = hvA;
        *(half8*)(&sh1[wv * 2 + 1][fl * 8]) = hvB;
    }
    __syncthreads();

    // --- MFMA gemm2: rows node0..node0+15; wave wv computes col-tile wv.
    const int quad = lane >> 4;
    const int l16  = lane & 15;
    float4v acc0 = {};
#pragma unroll
    for (int kc = 0; kc < 4; kc++) {
        const int k0 = kc * 32;
        half8 a = *(const half8*)(&sh1[l16][k0 + quad * 8]);
        const float* wp = W2 + (size_t)(k0 + quad * 8) * 128 + wv * 16 + l16;
        half8 b;
#pragma unroll
        for (int jj = 0; jj < 8; jj++) b[jj] = (_Float16)wp[jj * 128];
        acc0 = __builtin_amdgcn_mfma_f32_16x16x32_f16(a, b, acc0, 0, 0, 0);
    }
#pragma unroll
    for (int r = 0; r < 4; r++) {
        int row = node0 + quad * 4 + r;
        int rn; float s;
        unpack_pd(packed[row], rn, s);
        x2[(size_t)row * 128 + wv * 16 + l16] = f32_fp8(acc0[r] * s);
    }
}

// ---------------------------------------------------------------------------
// Layer-2 agg + head dot, full-row uint2 dword-gather. 256 thr = 4 waves,
// 2 nodes/wave -> 8 nodes/block; 6250 blocks.
// ---------------------------------------------------------------------------
__global__ __launch_bounds__(256) void agg_head_kernel(const unsigned char* __restrict__ x8,
                                                       const unsigned long long* __restrict__ packed,
                                                       const unsigned int* __restrict__ bucket,
                                                       const float* __restrict__ bias,
                                                       const float* __restrict__ Wh,
                                                       float* __restrict__ nodedot) {
    const int wv   = threadIdx.x >> 6;
    const int lane = threadIdx.x & 63;
    const int g    = lane >> 4;
    const int fl   = lane & 15;

    const int nodeA = blockIdx.x * 8 + wv * 2;
    const int nodeB = nodeA + 1;
    int nA; float dvA; unpack_pd(packed[nodeA], nA, dvA);
    int nB; float dvB; unpack_pd(packed[nodeB], nB, dvB);

    unsigned ehA = (lane < nA) ? __builtin_nontemporal_load(&bucket[(size_t)nodeA * CAP + lane]) : 0u;
    unsigned ehB = (lane < nB) ? __builtin_nontemporal_load(&bucket[(size_t)nodeB * CAP + lane]) : 0u;
    int eiA = (int)ehA, eiB = (int)ehB;
    int nmax = nA > nB ? nA : nB;

    const unsigned char* base = x8 + fl * 8;

    float aA[8] = {}, aB[8] = {};
    for (int i = 0; i < nmax; i += 8) {
        unsigned hA0 = (unsigned)__shfl(eiA, i + g);
        unsigned hA1 = (unsigned)__shfl(eiA, i + 4 + g);
        unsigned hB0 = (unsigned)__shfl(eiB, i + g);
        unsigned hB1 = (unsigned)__shfl(eiB, i + 4 + g);
        uint2 dA0 = *(const uint2*)(base + (size_t)(hA0 & 0xFFFFu) * 128);
        uint2 dA1 = *(const uint2*)(base + (size_t)(hA1 & 0xFFFFu) * 128);
        uint2 dB0 = *(const uint2*)(base + (size_t)(hB0 & 0xFFFFu) * 128);
        uint2 dB1 = *(const uint2*)(base + (size_t)(hB1 & 0xFFFFu) * 128);
        float vA0 = hu2f((unsigned short)(hA0 >> 16));
        float vA1 = hu2f((unsigned short)(hA1 >> 16));
        float vB0 = hu2f((unsigned short)(hB0 >> 16));
        float vB1 = hu2f((unsigned short)(hB1 >> 16));
#pragma unroll
        for (int d = 0; d < 2; d++) {
            unsigned wA0 = d ? dA0.y : dA0.x;
            unsigned wA1 = d ? dA1.y : dA1.x;
            unsigned wB0 = d ? dB0.y : dB0.x;
            unsigned wB1 = d ? dB1.y : dB1.x;
            f32x2 A0lo = __builtin_amdgcn_cvt_pk_f32_fp8((int)wA0, false);
            f32x2 A0hi = __builtin_amdgcn_cvt_pk_f32_fp8((int)wA0, true);
            f32x2 A1lo = __builtin_amdgcn_cvt_pk_f32_fp8((int)wA1, false);
            f32x2 A1hi = __builtin_amdgcn_cvt_pk_f32_fp8((int)wA1, true);
            f32x2 B0lo = __builtin_amdgcn_cvt_pk_f32_fp8((int)wB0, false);
            f32x2 B0hi = __builtin_amdgcn_cvt_pk_f32_fp8((int)wB0, true);
            f32x2 B1lo = __builtin_amdgcn_cvt_pk_f32_fp8((int)wB1, false);
            f32x2 B1hi = __builtin_amdgcn_cvt_pk_f32_fp8((int)wB1, true);
            aA[d*4+0] += vA0 * A0lo[0] + vA1 * A1lo[0];
            aA[d*4+1] += vA0 * A0lo[1] + vA1 * A1lo[1];
            aA[d*4+2] += vA0 * A0hi[0] + vA1 * A1hi[0];
            aA[d*4+3] += vA0 * A0hi[1] + vA1 * A1hi[1];
            aB[d*4+0] += vB0 * B0lo[0] + vB1 * B1lo[0];
            aB[d*4+1] += vB0 * B0lo[1] + vB1 * B1lo[1];
            aB[d*4+2] += vB0 * B0hi[0] + vB1 * B1hi[0];
            aB[d*4+3] += vB0 * B0hi[1] + vB1 * B1hi[1];
        }
    }

#pragma unroll
    for (int k = 0; k < 8; k++) {
        aA[k] += __shfl_xor(aA[k], 16, 64);
        aA[k] += __shfl_xor(aA[k], 32, 64);
        aB[k] += __shfl_xor(aB[k], 16, 64);
        aB[k] += __shfl_xor(aB[k], 32, 64);
    }

    {
        uint2 dsA = *(const uint2*)(base + (size_t)nodeA * 128);
        uint2 dsB = *(const uint2*)(base + (size_t)nodeB * 128);
#pragma unroll
        for (int d = 0; d < 2; d++) {
            unsigned wA = d ? dsA.y : dsA.x;
            unsigned wB = d ? dsB.y : dsB.x;
            f32x2 Alo = __builtin_amdgcn_cvt_pk_f32_fp8((int)wA, false);
            f32x2 Ahi = __builtin_amdgcn_cvt_pk_f32_fp8((int)wA, true);
            f32x2 Blo = __builtin_amdgcn_cvt_pk_f32_fp8((int)wB, false);
            f32x2 Bhi = __builtin_amdgcn_cvt_pk_f32_fp8((int)wB, true);
            aA[d*4+0] += Alo[0]; aA[d*4+1] += Alo[1];
            aA[d*4+2] += Ahi[0]; aA[d*4+3] += Ahi[1];
            aB[d*4+0] += Blo[0]; aB[d*4+1] += Blo[1];
            aB[d*4+2] += Bhi[0]; aB[d*4+3] += Bhi[1];
        }
    }

    float4 bb0 = ((const float4*)bias)[fl * 2];
    float4 bb1 = ((const float4*)bias)[fl * 2 + 1];
    float4 wh0 = ((const float4*)Wh)[fl * 2];
    float4 wh1 = ((const float4*)Wh)[fl * 2 + 1];
    float bb[8] = {bb0.x, bb0.y, bb0.z, bb0.w, bb1.x, bb1.y, bb1.z, bb1.w};
    float ww[8] = {wh0.x, wh0.y, wh0.z, wh0.w, wh1.x, wh1.y, wh1.z, wh1.w};
    float sA = 0.0f, sB = 0.0f;
#pragma unroll
    for (int k = 0; k < 8; k++) {
        sA += fmaxf(dvA * aA[k] + bb[k], 0.0f) * ww[k];
        sB += fmaxf(dvB * aB[k] + bb[k], 0.0f) * ww[k];
    }
    // reduce over fl (16 lanes/group; groups hold identical values)
#pragma unroll
    for (int off = 8; off > 0; off >>= 1) {
        sA += __shfl_xor(sA, off, 64);
        sB += __shfl_xor(sB, off, 64);
    }
    if (lane == 0) {
        nodedot[nodeA] = sA;
        nodedot[nodeB] = sB;
    }
}

// ---------------------------------------------------------------------------
// out[g] = (sum nodedot over graph)/cnt + bh; bounds via binary search.
// ---------------------------------------------------------------------------
__global__ __launch_bounds__(256) void final2_kernel(const float* __restrict__ nodedot,
                                                     const int* __restrict__ batch,
                                                     const float* __restrict__ bh,
                                                     float* __restrict__ out) {
    __shared__ float red[256];
    int g = blockIdx.x;
    int lo = 0, hi = N_NODES;
    while (lo < hi) { int mid = (lo + hi) >> 1; if (batch[mid] < g) lo = mid + 1; else hi = mid; }
    int a = lo;
    hi = N_NODES;
    while (lo < hi) { int mid = (lo + hi) >> 1; if (batch[mid] < g + 1) lo = mid + 1; else hi = mid; }
    int b = lo;

    float s = 0.0f;
    for (int n = a + threadIdx.x; n < b; n += 256) s += nodedot[n];
    red[threadIdx.x] = s;
    __syncthreads();
#pragma unroll
    for (int off = 128; off > 0; off >>= 1) {
        if (threadIdx.x < off) red[threadIdx.x] += red[threadIdx.x + off];
        __syncthreads();
    }
    if (threadIdx.x == 0)
        out[g] = red[0] / fmaxf((float)(b - a), 1.0f) + bh[0];
}

// ---------------------------------------------------------------------------
extern "C" void kernel_launch(void* const* d_in, const int* in_sizes, int n_in,
                              void* d_out, int out_size, void* d_ws, size_t ws_size,
                              hipStream_t stream) {
    const float* x   = (const float*)d_in[0];
    const float* ew  = (const float*)d_in[1];
    const float* W1  = (const float*)d_in[2];
    const float* b1  = (const float*)d_in[3];
    const float* W2  = (const float*)d_in[4];
    const float* b2  = (const float*)d_in[5];
    const float* Wh  = (const float*)d_in[6];
    const float* bh  = (const float*)d_in[7];
    const int*   ei  = (const int*)d_in[8];
    const int*   bat = (const int*)d_in[9];
    float* out = (float*)d_out;

    char* ws = (char*)d_ws;
    unsigned char* bufA8 = (unsigned char*)ws;            ws += (size_t)N_NODES * D;
    unsigned char* bufB8 = (unsigned char*)ws;            ws += (size_t)N_NODES * D;
    ws += 128 - ((size_t)ws & 127);                       // realign
    unsigned int* bucket = (unsigned int*)ws;             ws += (size_t)N_NODES * CAP * 4;
    unsigned long long* packed = (unsigned long long*)ws; ws += (size_t)N_NODES * 8;
    float*  nodedot = (float*)ws;                         ws += (size_t)N_NODES * 4;

    hipMemsetAsync(packed, 0, (size_t)N_NODES * 8, stream);

    // gemm1 (x@W1 -> fp8 rows via MFMA fp16) overlapped with fill
    fused_gemm1_fill<<<NB_GEMM1 + NB_FILL, 256, 0, stream>>>(x, W1, bufA8, ei, ew, packed, bucket);

    // layer 1 agg (full-row uint2 gather) + gemm2 fused -> x2 fp8 rows
    agg1_gemm2_kernel<<<NB_AGG16, 512, 0, stream>>>(bufA8, packed, bucket, b1, W2, bufB8);

    // layer 2 agg (full-row uint2 gather) + head dot
    agg_head_kernel<<<6250, 256, 0, stream>>>(bufB8, packed, bucket, b2, Wh, nodedot);

    // segment-sum + head bias
    final2_kernel<<<N_GRAPHS, 256, 0, stream>>>(nodedot, bat, bh, out);
}